// Round 2
// baseline (231.956 us; speedup 1.0000x reference)
//
#include <hip/hip_runtime.h>
#include <math.h>

// YOLOv1 loss: predicts/targets (8192, 7, 7, 30) fp32 -> scalar.
// Memory-bound streaming reduction, roofline ~15.3 us @ 6.3 TB/s for 96.3 MB.
// v4 (from v3's async global_load_lds staging):
//   - 128-cell / 128-thread blocks: LDS 30720 B -> 5 blocks/CU (was 2 at
//     61440 B). 5-way phase interleave keeps HBM busy through each block's
//     vmcnt(0) drain + compute phase.
//   - Staging: 30 x 1024 B chunks; wave 0 stages the p-tile, wave 1 the
//     t-tile, 15 uniform global_load_lds(width=16) each. LDS stays LINEAR
//     (global_load_lds writes wave-uniform base + lane*16).
//   - Single launch: last-block-done ticket fuses the final reduction
//     (ticket counter zeroed by a 4 B hipMemsetAsync; workspace is
//     re-poisoned between iterations so it can't be assumed zero).
//     Writer: store partial -> __threadfence (agent release, L2 wb) ->
//     atomicAdd ticket. Last block: __threadfence (acquire, L2 inv, needed
//     for cross-XCD visibility) -> fixed-order reduce -> out. Deterministic.

#define S7 7
#define CCH 30
#define CELLS_PER_BLOCK 128
#define THREADS 128
#define N_CELLS (8192 * S7 * S7)             // 401408
#define N_BLOCKS (N_CELLS / CELLS_PER_BLOCK) // 3136 exactly
#define EPSV 1e-6f

__device__ __forceinline__ float iou_cxcywh(float acx, float acy, float aw, float ah,
                                            float bcx, float bcy, float bw, float bh) {
    float ax1 = acx - aw * 0.5f, ax2 = acx + aw * 0.5f;
    float ay1 = acy - ah * 0.5f, ay2 = acy + ah * 0.5f;
    float bx1 = bcx - bw * 0.5f, bx2 = bcx + bw * 0.5f;
    float by1 = bcy - bh * 0.5f, by2 = bcy + bh * 0.5f;
    float iw = fmaxf(fminf(ax2, bx2) - fmaxf(ax1, bx1), 0.0f);
    float ih = fmaxf(fminf(ay2, by2) - fmaxf(ay1, by1), 0.0f);
    float inter = iw * ih;
    float area_a = (ax2 - ax1) * (ay2 - ay1);
    float area_b = (bx2 - bx1) * (by2 - by1);
    return inter / (area_a + area_b - inter);
}

__global__ __launch_bounds__(THREADS) void yolo_loss_fused(const float* __restrict__ pred,
                                                           const float* __restrict__ targ,
                                                           float* __restrict__ partial,
                                                           unsigned int* __restrict__ ticket,
                                                           float* __restrict__ out) {
    // p-tile: smem[0 .. 3840), t-tile: smem[3840 .. 7680)  (30720 B)
    __shared__ float smem[2 * CELLS_PER_BLOCK * CCH];
    __shared__ float red[2];
    __shared__ int is_last;

    const int tid = threadIdx.x;
    const int lane = tid & 63;
    const int wid = tid >> 6;                 // wave 0..1
    const int block_cell0 = blockIdx.x * CELLS_PER_BLOCK;

    // ---- Stage: async global->LDS, 30 chunks x 1024 B, 15 per wave ----
    // wave 0 -> p-tile (chunks 0..14), wave 1 -> t-tile (chunks 15..29).
    // All addresses 16B-aligned (block base = 15360 B * blockIdx).
    {
        const float* gbase = (wid == 0) ? (pred + (size_t)block_cell0 * CCH)
                                        : (targ + (size_t)block_cell0 * CCH);
        float* lbase = smem + wid * (CELLS_PER_BLOCK * CCH);
#pragma unroll
        for (int i = 0; i < 15; ++i) {
            const float* gsrc = gbase + i * 256 + lane * 4;
            float* ldst = lbase + i * 256;    // wave-uniform base; HW adds lane*16
            __builtin_amdgcn_global_load_lds(
                (const __attribute__((address_space(1))) void*)gsrc,
                (__attribute__((address_space(3))) void*)ldst,
                16, 0, 0);
        }
    }
    __syncthreads();   // compiler emits s_waitcnt vmcnt(0) before s_barrier

    // ---- Compute: one cell per thread ----
    const float* p = smem + tid * CCH;
    const float* t = smem + CELLS_PER_BLOCK * CCH + tid * CCH;
    const int cell = block_cell0 + tid;
    const int xy = cell % (S7 * S7);
    const float fx = (float)(xy % S7);
    const float fy = (float)(xy / S7);
    const float ratio = 1.0f / 7.0f;

    float px1 = p[0], py1 = p[1], pw1 = p[2], ph1 = p[3], pc1 = p[4];
    float px2 = p[5], py2 = p[6], pw2 = p[7], ph2 = p[8], pc2 = p[9];
    float tx = t[0], ty = t[1], tw = t[2], th = t[3], tc = t[4];
    bool obj = tc > 0.0f;

    float tcx = (tx + fx) * ratio, tcy = (ty + fy) * ratio;
    float iou1 = iou_cxcywh((px1 + fx) * ratio, (py1 + fy) * ratio, pw1, ph1,
                            tcx, tcy, tw, th);
    float iou2 = iou_cxcywh((px2 + fx) * ratio, (py2 + fy) * ratio, pw2, ph2,
                            tcx, tcy, tw, th);
    bool resp = iou1 > iou2;

    // class SSE (channels 10..29)
    float cls = 0.0f;
#pragma unroll
    for (int k = 10; k < 30; ++k) {
        float d = p[k] - t[k];
        cls += d * d;
    }

    float loss;
    if (obj) {
        float sx, sy, sw, sh, sc, siou;
        if (resp) { sx = px1; sy = py1; sw = pw1; sh = ph1; sc = pc1; siou = iou1; }
        else      { sx = px2; sy = py2; sw = pw2; sh = ph2; sc = pc2; siou = iou2; }
        float dx = sx - tx, dy = sy - ty;
        float dw = sqrtf(fmaxf(sw, EPSV)) - sqrtf(fmaxf(tw, EPSV));
        float dh = sqrtf(fmaxf(sh, EPSV)) - sqrtf(fmaxf(th, EPSV));
        float dc = sc - siou;
        loss = 5.0f * (dx * dx + dy * dy + dw * dw + dh * dh) + dc * dc + cls;
    } else {
        loss = 0.5f * (pc1 * pc1 + pc2 * pc2);
    }

    // ---- Block reduction: wave-64 shuffle, then 2 wave partials via LDS ----
    float v = loss;
#pragma unroll
    for (int off = 32; off > 0; off >>= 1) v += __shfl_down(v, off);

    if (lane == 0) red[wid] = v;
    __syncthreads();

    // ---- Publish block sum + take a ticket (last-block-done pattern) ----
    if (tid == 0) {
        partial[blockIdx.x] = red[0] + red[1];
        __threadfence();                       // release: block sum visible device-wide
        unsigned int old = atomicAdd(ticket, 1u);
        is_last = (old == (unsigned int)(N_BLOCKS - 1));
    }
    __syncthreads();

    // ---- Last block reduces all partials in fixed index order ----
    if (is_last) {
        __threadfence();                       // acquire: see all blocks' partials
        float s = 0.0f;
        for (int i = tid; i < N_BLOCKS; i += THREADS) s += partial[i];
#pragma unroll
        for (int off = 32; off > 0; off >>= 1) s += __shfl_down(s, off);
        if (lane == 0) red[wid] = s;
        __syncthreads();
        if (tid == 0) out[0] = red[0] + red[1];
    }
}

extern "C" void kernel_launch(void* const* d_in, const int* in_sizes, int n_in,
                              void* d_out, int out_size, void* d_ws, size_t ws_size,
                              hipStream_t stream) {
    const float* predicts = (const float*)d_in[0];
    const float* targets  = (const float*)d_in[1];
    float* out = (float*)d_out;
    float* partial = (float*)d_ws;                              // 3136 floats
    unsigned int* ticket = (unsigned int*)((char*)d_ws + (size_t)N_BLOCKS * 4);

    // Workspace is re-poisoned between iterations: ticket must start at 0.
    hipMemsetAsync(ticket, 0, 4, stream);
    yolo_loss_fused<<<N_BLOCKS, THREADS, 0, stream>>>(predicts, targets, partial, ticket, out);
}

// Round 3
// 113.143 us; speedup vs baseline: 2.0501x; 2.0501x over previous
//
#include <hip/hip_runtime.h>
#include <math.h>

// YOLOv1 loss: predicts/targets (8192, 7, 7, 30) fp32 -> scalar.
// v5: REVERT round-2 fusion (per-block __threadfence + same-address atomics
//     cost ~145 us even with zero memory traffic — structural serialization).
//     Back to the deterministic two-kernel structure.
// v5 change vs v3: NO LDS staging. Round-2 counters showed FETCH_SIZE ~ 0 in
//     steady state — the 96 MB of inputs are Infinity-Cache resident, so LDS
//     staging (a pure coalescing device; this kernel has zero reuse) only
//     buys its costs: vmcnt(0) drain + barrier + 30 ds_reads/thread + a
//     2-blocks/CU LDS occupancy cap. Direct float2 register loads instead:
//     cell base = 120 B (8 B aligned -> dwordx2 legal, dwordx4 not); a
//     wave's 64 lanes consume every byte of the ~60 cache lines each load
//     touches, and the data is L3-hot. No __syncthreads until reduction;
//     occupancy VGPR-bound; 25 independent loads/thread hide latency.
//     t-channels 6..9 are never used by the reference -> skipped.

#define S7 7
#define CCH 30
#define THREADS 256
#define N_CELLS (8192 * S7 * S7)             // 401408
#define N_BLOCKS (N_CELLS / THREADS)         // 1568 exactly
#define EPSV 1e-6f

__device__ __forceinline__ float iou_cxcywh(float acx, float acy, float aw, float ah,
                                            float bcx, float bcy, float bw, float bh) {
    float ax1 = acx - aw * 0.5f, ax2 = acx + aw * 0.5f;
    float ay1 = acy - ah * 0.5f, ay2 = acy + ah * 0.5f;
    float bx1 = bcx - bw * 0.5f, bx2 = bcx + bw * 0.5f;
    float by1 = bcy - bh * 0.5f, by2 = bcy + bh * 0.5f;
    float iw = fmaxf(fminf(ax2, bx2) - fmaxf(ax1, bx1), 0.0f);
    float ih = fmaxf(fminf(ay2, by2) - fmaxf(ay1, by1), 0.0f);
    float inter = iw * ih;
    float area_a = (ax2 - ax1) * (ay2 - ay1);
    float area_b = (bx2 - bx1) * (by2 - by1);
    return inter / (area_a + area_b - inter);
}

__global__ __launch_bounds__(THREADS) void yolo_loss_partial(const float* __restrict__ pred,
                                                             const float* __restrict__ targ,
                                                             float* __restrict__ partial) {
    const int tid = threadIdx.x;
    const int cell = blockIdx.x * THREADS + tid;

    // 8-byte-aligned vector views of this thread's cell (30 floats = 15 float2)
    const float2* p2 = (const float2*)(pred + (size_t)cell * CCH);
    const float2* t2 = (const float2*)(targ + (size_t)cell * CCH);

    // box channels: p 0..9, t 0..4
    float2 pA = p2[0], pB = p2[1], pC = p2[2], pD = p2[3], pE = p2[4];
    float2 tA = t2[0], tB = t2[1], tC = t2[2];

    float px1 = pA.x, py1 = pA.y, pw1 = pB.x, ph1 = pB.y, pc1 = pC.x;
    float px2 = pC.y, py2 = pD.x, pw2 = pD.y, ph2 = pE.x, pc2 = pE.y;
    float tx = tA.x, ty = tA.y, tw = tB.x, th = tB.y, tc = tC.x;
    bool obj = tc > 0.0f;

    // class SSE (channels 10..29 = float2 indices 5..14)
    float cls = 0.0f;
#pragma unroll
    for (int k = 5; k < 15; ++k) {
        float2 pk = p2[k], tk = t2[k];
        float dx = pk.x - tk.x, dy = pk.y - tk.y;
        cls = fmaf(dx, dx, cls);
        cls = fmaf(dy, dy, cls);
    }

    const int xy = cell % (S7 * S7);
    const float fx = (float)(xy % S7);
    const float fy = (float)(xy / S7);
    const float ratio = 1.0f / 7.0f;

    float tcx = (tx + fx) * ratio, tcy = (ty + fy) * ratio;
    float iou1 = iou_cxcywh((px1 + fx) * ratio, (py1 + fy) * ratio, pw1, ph1,
                            tcx, tcy, tw, th);
    float iou2 = iou_cxcywh((px2 + fx) * ratio, (py2 + fy) * ratio, pw2, ph2,
                            tcx, tcy, tw, th);
    bool resp = iou1 > iou2;

    float loss;
    if (obj) {
        float sx, sy, sw, sh, sc, siou;
        if (resp) { sx = px1; sy = py1; sw = pw1; sh = ph1; sc = pc1; siou = iou1; }
        else      { sx = px2; sy = py2; sw = pw2; sh = ph2; sc = pc2; siou = iou2; }
        float dx = sx - tx, dy = sy - ty;
        float dw = sqrtf(fmaxf(sw, EPSV)) - sqrtf(fmaxf(tw, EPSV));
        float dh = sqrtf(fmaxf(sh, EPSV)) - sqrtf(fmaxf(th, EPSV));
        float dc = sc - siou;
        loss = 5.0f * (dx * dx + dy * dy + dw * dw + dh * dh) + dc * dc + cls;
    } else {
        loss = 0.5f * (pc1 * pc1 + pc2 * pc2);
    }

    // ---- Block reduction: wave-64 shuffle, then 4 wave partials via LDS ----
    float v = loss;
#pragma unroll
    for (int off = 32; off > 0; off >>= 1) v += __shfl_down(v, off);

    __shared__ float red[4];
    const int lane = tid & 63;
    const int wid = tid >> 6;
    if (lane == 0) red[wid] = v;
    __syncthreads();
    if (tid == 0) partial[blockIdx.x] = red[0] + red[1] + red[2] + red[3];
}

__global__ __launch_bounds__(256) void yolo_loss_final(const float* __restrict__ partial,
                                                       float* __restrict__ out) {
    float v = 0.0f;
    for (int i = threadIdx.x; i < N_BLOCKS; i += 256) v += partial[i];
#pragma unroll
    for (int off = 32; off > 0; off >>= 1) v += __shfl_down(v, off);

    __shared__ float red[4];
    const int lane = threadIdx.x & 63;
    const int wid = threadIdx.x >> 6;
    if (lane == 0) red[wid] = v;
    __syncthreads();
    if (threadIdx.x == 0) out[0] = red[0] + red[1] + red[2] + red[3];
}

extern "C" void kernel_launch(void* const* d_in, const int* in_sizes, int n_in,
                              void* d_out, int out_size, void* d_ws, size_t ws_size,
                              hipStream_t stream) {
    const float* predicts = (const float*)d_in[0];
    const float* targets  = (const float*)d_in[1];
    float* out = (float*)d_out;
    float* partial = (float*)d_ws;   // N_BLOCKS floats = 6272 B

    yolo_loss_partial<<<N_BLOCKS, THREADS, 0, stream>>>(predicts, targets, partial);
    yolo_loss_final<<<1, 256, 0, stream>>>(partial, out);
}